// Round 4
// baseline (236.006 us; speedup 1.0000x reference)
//
#include <hip/hip_runtime.h>

// LightweightConv1d: y[b,t,c] = sum_k softmax(w)[c%H,k] * x[b, t+k-PAD, c]
// x: (B,T,C) fp32 contiguous (C innermost), w: (H,1,K) fp32, y: (B,T,C) fp32.
// R1: sliding window depth-1 prefetch -> 85 us, latency-bound.
// R2: 14-row batch load, TCHUNK=8 -> 81 us; L1 traffic 4.4 TB/s (7.2 B/cy/CU),
//     1.75x halo read amplification eats the budget.
// R3: 64-row stripe per block, 8-row pipelined chunks (amp 1.09x), nontemporal
//     stores. 512 blocks x 256 thr. (R3 failed compile: nontemporal builtin
//     needs clang ext_vector, not HIP_vector_type -> fixed in R4.)

typedef float v4f __attribute__((ext_vector_type(4)));

constexpr int B_     = 8;
constexpr int T_     = 4096;
constexpr int C_     = 1024;
constexpr int H_     = 16;
constexpr int K_     = 7;
constexpr int PAD_   = 3;
constexpr int STRIPE = 64;              // t-rows per block
constexpr int TCH    = 8;               // outputs per chunk
constexpr int WIN    = TCH + K_ - 1;    // 14-row register window
constexpr int NCHUNK = STRIPE / TCH;    // 8
constexpr int C4     = C_ / 4;          // 256 v4f per row == blockDim.x

__global__ __launch_bounds__(256) void lwconv_kernel(
    const float* __restrict__ x, const float* __restrict__ w,
    float* __restrict__ y) {
  __shared__ float ws[H_][K_];
  const int tid = threadIdx.x;

  // Per-head softmax over K (112 values; threads 0..15 do one head each).
  if (tid < H_) {
    float v[K_];
    float m = -1e30f;
#pragma unroll
    for (int k = 0; k < K_; ++k) { v[k] = w[tid * K_ + k]; m = fmaxf(m, v[k]); }
    float s = 0.f;
#pragma unroll
    for (int k = 0; k < K_; ++k) { v[k] = expf(v[k] - m); s += v[k]; }
    const float inv = 1.f / s;
#pragma unroll
    for (int k = 0; k < K_; ++k) ws[tid][k] = v[k] * inv;
  }
  __syncthreads();

  // Thread handles channels 4*tid..4*tid+3; heads h0..h0+3 (4 | 16, no wrap).
  const int h0 = (4 * tid) & (H_ - 1);
  float wr[4][K_];
#pragma unroll
  for (int j = 0; j < 4; ++j)
#pragma unroll
    for (int k = 0; k < K_; ++k) wr[j][k] = ws[h0 + j][k];

  const int stripes = T_ / STRIPE;        // 64
  const int b  = blockIdx.x / stripes;
  const int s0 = (blockIdx.x % stripes) * STRIPE;

  const v4f* __restrict__ xr =
      reinterpret_cast<const v4f*>(x + (size_t)b * T_ * C_) + tid;
  v4f* __restrict__ yr =
      reinterpret_cast<v4f*>(y + (size_t)b * T_ * C_) + tid;

  const v4f z4 = {0.f, 0.f, 0.f, 0.f};

  // Register window: win[i] = row s0 - PAD + i (current chunk base t0 = s0).
  v4f win[WIN];
#pragma unroll
  for (int i = 0; i < WIN; ++i) {
    const int t = s0 - PAD_ + i;
    win[i] = (t >= 0 && t < T_) ? xr[(size_t)t * C4] : z4;
  }

  v4f nxt[TCH];

  auto compute_chunk = [&](int t0) {
#pragma unroll
    for (int tt = 0; tt < TCH; ++tt) {
      float ax = 0.f, ay = 0.f, az = 0.f, aw = 0.f;
#pragma unroll
      for (int k = 0; k < K_; ++k) {
        ax = fmaf(win[tt + k].x, wr[0][k], ax);
        ay = fmaf(win[tt + k].y, wr[1][k], ay);
        az = fmaf(win[tt + k].z, wr[2][k], az);
        aw = fmaf(win[tt + k].w, wr[3][k], aw);
      }
      const v4f out = {ax, ay, az, aw};
      __builtin_nontemporal_store(out, &yr[(size_t)(t0 + tt) * C4]);
    }
  };

#pragma unroll 1
  for (int chunk = 0; chunk < NCHUNK - 1; ++chunk) {
    const int t0 = s0 + chunk * TCH;
    // Issue next chunk's 8 new rows (t0+11 .. t0+18) before computing;
    // compute below depends only on win[] -> loads stay in flight (vmcnt(8)).
#pragma unroll
    for (int i = 0; i < TCH; ++i) {
      const int t = t0 + (WIN - PAD_) + i;
      nxt[i] = (t < T_) ? xr[(size_t)t * C4] : z4;
    }
    compute_chunk(t0);
    // Shift window down by TCH, append the prefetched rows.
#pragma unroll
    for (int i = 0; i < WIN - TCH; ++i) win[i] = win[i + TCH];
#pragma unroll
    for (int i = 0; i < TCH; ++i) win[WIN - TCH + i] = nxt[i];
  }
  // Final chunk of the stripe: no prefetch.
  compute_chunk(s0 + (NCHUNK - 1) * TCH);
}

extern "C" void kernel_launch(void* const* d_in, const int* in_sizes, int n_in,
                              void* d_out, int out_size, void* d_ws, size_t ws_size,
                              hipStream_t stream) {
  const float* x = (const float*)d_in[0];   // (B,T,C) fp32
  const float* w = (const float*)d_in[1];   // (H,1,K) fp32
  float* y = (float*)d_out;                 // (B,T,C) fp32

  const int grid = B_ * (T_ / STRIPE);      // 512 blocks
  lwconv_kernel<<<grid, 256, 0, stream>>>(x, w, y);
}